// Round 3
// baseline (172.857 us; speedup 1.0000x reference)
//
#include <hip/hip_runtime.h>
#include <stdint.h>
#include <math.h>

typedef __attribute__((ext_vector_type(8))) __bf16 bf16x8;
typedef __attribute__((ext_vector_type(4))) __bf16 bf16x4;
typedef __attribute__((ext_vector_type(4))) float f32x4;

// async global->LDS 16B DMA (no VGPR round-trip). LDS dest must be
// wave-uniform base; HW writes lane i at base + i*16.
__device__ __forceinline__ void gload_lds16(const __bf16* g, __bf16* l) {
  __builtin_amdgcn_global_load_lds(
      (const __attribute__((address_space(1))) unsigned int*)g,
      (__attribute__((address_space(3))) unsigned int*)l,
      16, 0, 0);
}

// ---------------- gates: softmax(x @ W_aux^T + b_aux) ----------------
__global__ __launch_bounds__(256) void k_gates(const float* __restrict__ x,
                                               const float* __restrict__ Waux,
                                               const float* __restrict__ baux,
                                               float* __restrict__ gates) {
  const int wave = threadIdx.x >> 6;
  const int lane = threadIdx.x & 63;
  const int row = blockIdx.x * 4 + wave;
  const float4* xr = (const float4*)(x + (size_t)row * 512);
  const float4* w0 = (const float4*)(Waux);
  const float4* w1 = (const float4*)(Waux + 512);
  float p0 = 0.f, p1 = 0.f;
  for (int c = lane; c < 128; c += 64) {
    float4 xv = xr[c];
    float4 a = w0[c], b = w1[c];
    p0 += xv.x * a.x + xv.y * a.y + xv.z * a.z + xv.w * a.w;
    p1 += xv.x * b.x + xv.y * b.y + xv.z * b.z + xv.w * b.w;
  }
  for (int off = 32; off; off >>= 1) {
    p0 += __shfl_down(p0, off, 64);
    p1 += __shfl_down(p1, off, 64);
  }
  if (lane == 0) {
    p0 += baux[0]; p1 += baux[1];
    float m = fmaxf(p0, p1);
    float e0 = __expf(p0 - m), e1 = __expf(p1 - m);
    float inv = 1.f / (e0 + e1);
    gates[row * 2 + 0] = e0 * inv;
    gates[row * 2 + 1] = e1 * inv;
  }
}

// ---------------- outs GEMM: C[m][n] = sum_k x[m][k] * Wflat[n][k] + bias[n] ----
// M=4096, N=512, K=512. 64x64 tiles -> grid (8,64)=512 blocks (2 blocks/CU).
// 4 waves in 2x2, each wave 32x32 via 16x16x32 mfma. XOR-swizzled LDS +
// register prefetch (small live set, no spill — verified R1/R2).
__global__ __launch_bounds__(256) void k_outs(const float* __restrict__ x,
                                              const float* __restrict__ W,
                                              const float* __restrict__ bias,
                                              __bf16* __restrict__ totalbf) {
  __shared__ __bf16 As[64][64];
  __shared__ __bf16 Bs[64][64];
  const int bj = blockIdx.x;   // 0..7  (N tiles of 64)
  const int bi = blockIdx.y;   // 0..63 (M tiles of 64)
  const int t = threadIdx.x;
  const int wid = t >> 6, lane = t & 63;
  const int wr = wid >> 1, wc = wid & 1;
  const int n16 = lane & 15, q = lane >> 4;
  const int sx = (n16 & 7) << 3;        // read-side swizzle (element units)
  const int erow = t >> 4;              // 0..15 (+p*16)
  const int c4 = (t & 15) << 2;         // 0..60

  f32x4 acc[2][2];
  f32x4 zero = {0.f, 0.f, 0.f, 0.f};
  for (int i = 0; i < 2; ++i)
    for (int j = 0; j < 2; ++j) acc[i][j] = zero;

  const int arow0 = bi * 64, brow0 = bj * 64;

  float4 ra[4], rb[4];
#pragma unroll
  for (int p = 0; p < 4; ++p) {
    int row = p * 16 + erow;
    ra[p] = *(const float4*)(x + (size_t)(arow0 + row) * 512 + c4);
    rb[p] = *(const float4*)(W + (size_t)(brow0 + row) * 512 + c4);
  }

  for (int kc = 0; kc < 512; kc += 64) {
#pragma unroll
    for (int p = 0; p < 4; ++p) {
      int row = p * 16 + erow;
      int col = c4 ^ ((row & 7) << 3);
      float4 va = ra[p];
      bf16x4 ba = {(__bf16)va.x, (__bf16)va.y, (__bf16)va.z, (__bf16)va.w};
      *(bf16x4*)&As[row][col] = ba;
      float4 vb = rb[p];
      bf16x4 bb = {(__bf16)vb.x, (__bf16)vb.y, (__bf16)vb.z, (__bf16)vb.w};
      *(bf16x4*)&Bs[row][col] = bb;
    }
    if (kc < 448) {
#pragma unroll
      for (int p = 0; p < 4; ++p) {
        int row = p * 16 + erow;
        ra[p] = *(const float4*)(x + (size_t)(arow0 + row) * 512 + kc + 64 + c4);
        rb[p] = *(const float4*)(W + (size_t)(brow0 + row) * 512 + kc + 64 + c4);
      }
    }
    __syncthreads();
#pragma unroll
    for (int ks = 0; ks < 2; ++ks) {
      bf16x8 af[2], bfr[2];
#pragma unroll
      for (int f = 0; f < 2; ++f) {
        af[f]  = *(const bf16x8*)&As[wr * 32 + f * 16 + n16][(ks * 32 + q * 8) ^ sx];
        bfr[f] = *(const bf16x8*)&Bs[wc * 32 + f * 16 + n16][(ks * 32 + q * 8) ^ sx];
      }
      for (int fr = 0; fr < 2; ++fr)
        for (int fc = 0; fc < 2; ++fc)
          acc[fr][fc] = __builtin_amdgcn_mfma_f32_16x16x32_bf16(af[fr], bfr[fc], acc[fr][fc], 0, 0, 0);
    }
    __syncthreads();
  }

  for (int fc = 0; fc < 2; ++fc) {
    int n_g = bj * 64 + wc * 32 + fc * 16 + n16;   // 0..511
    float bv = bias[n_g];
    int l = n_g >> 8, o = n_g & 255;
    for (int fr = 0; fr < 2; ++fr) {
      for (int r = 0; r < 4; ++r) {
        int m_g = bi * 64 + wr * 32 + fr * 16 + q * 4 + r;
        float v = acc[fr][fc][r] + bv;
        totalbf[(size_t)(l * 4096 + m_g) * 256 + o] = (__bf16)v;
      }
    }
  }
}

// ---------------- fused: sq (both halves) + colsum + combine -----------------
// 128 blocks x 256 thr; block handles 32 row-pairs (m, 4096+m). One pass over
// totalbf replaces the old k_sq + k_combine two passes.
__global__ __launch_bounds__(256) void k_sqc(const __bf16* __restrict__ tot,
                                             const float* __restrict__ gates,
                                             float* __restrict__ sq,
                                             float* __restrict__ colsum,
                                             float* __restrict__ out) {
  __shared__ float lcol[4][256];
  const int t = threadIdx.x;
  const int wave = t >> 6, lane = t & 63;
  float c0 = 0.f, c1 = 0.f, c2 = 0.f, c3 = 0.f;
  for (int it = 0; it < 8; ++it) {
    int m = blockIdx.x * 32 + wave * 8 + it;      // 0..4095
    bf16x4 v0 = *(const bf16x4*)(tot + (size_t)m * 256 + lane * 4);
    bf16x4 v1 = *(const bf16x4*)(tot + (size_t)(4096 + m) * 256 + lane * 4);
    float f00 = v0[0], f01 = v0[1], f02 = v0[2], f03 = v0[3];
    float f10 = v1[0], f11 = v1[1], f12 = v1[2], f13 = v1[3];
    float s0 = f00 * f00 + f01 * f01 + f02 * f02 + f03 * f03;
    float s1 = f10 * f10 + f11 * f11 + f12 * f12 + f13 * f13;
    for (int off = 32; off; off >>= 1) {
      s0 += __shfl_down(s0, off, 64);
      s1 += __shfl_down(s1, off, 64);
    }
    if (lane == 0) { sq[m] = s0; sq[4096 + m] = s1; }
    c0 += f00 + f10; c1 += f01 + f11; c2 += f02 + f12; c3 += f03 + f13;
    float2 gv = *(const float2*)(gates + m * 2);
    float4 r;
    r.x = gv.x * f00 + gv.y * f10;
    r.y = gv.x * f01 + gv.y * f11;
    r.z = gv.x * f02 + gv.y * f12;
    r.w = gv.x * f03 + gv.y * f13;
    *(float4*)(out + (size_t)m * 256 + lane * 4) = r;
  }
  lcol[wave][lane * 4 + 0] = c0;
  lcol[wave][lane * 4 + 1] = c1;
  lcol[wave][lane * 4 + 2] = c2;
  lcol[wave][lane * 4 + 3] = c3;
  __syncthreads();
  float s2 = lcol[0][t] + lcol[1][t] + lcol[2][t] + lcol[3][t];
  atomicAdd(&colsum[t], s2);
}

// ---------------- bandwidth: sum(dist) = 2n*sum(sq) - 2*||colsum||^2 ----------
__global__ __launch_bounds__(256) void k_bw(const float* __restrict__ sq,
                                            const float* __restrict__ colsum,
                                            float* __restrict__ scal) {
  __shared__ float red[256];
  const int t = threadIdx.x;
  float s = 0.f;
  for (int i = t; i < 8192; i += 256) s += sq[i];
  red[t] = s;
  __syncthreads();
  for (int off = 128; off; off >>= 1) { if (t < off) red[t] += red[t + off]; __syncthreads(); }
  float sumsq = red[0];
  __syncthreads();
  float c = colsum[t];
  red[t] = c * c;
  __syncthreads();
  for (int off = 128; off; off >>= 1) { if (t < off) red[t] += red[t + off]; __syncthreads(); }
  if (t == 0) {
    double sumdist = 2.0 * 8192.0 * (double)sumsq - 2.0 * (double)red[0];
    double bw = sumdist / (8192.0 * 8192.0 - 8192.0) / 4.0;   // / KERNEL_MUL^(5//2)
    scal[1] = (float)(1.4426950408889634 / (bw * 16.0));      // g4 * log2(e)
    scal[2] = (float)bw;
  }
}

// ---------------- Gram tiles + fused multi-bandwidth kernel sum ---------------
// Compact upper-triangle launch (2080 = 8 XCDs x 260, balanced, bijective).
// SINGLE-buffer LDS (34 KB) -> 4 blocks/CU = 4 waves/SIMD: latency hiding by
// block-level TLP instead of intra-block dbuf (which cost occupancy in R2).
// Per iter: DMA-stage chunk -> barrier (drain) -> MFMA (setprio) -> barrier.
// Pre-swizzled DMA source + XOR read swizzle: 0 bank conflicts.
// Last block (atomic counter) writes the final scalar -> k_final eliminated.
__global__ __launch_bounds__(256, 4) void k_gram(const __bf16* __restrict__ tot,
                                                 const float* __restrict__ sq,
                                                 const float* __restrict__ scal,
                                                 float* __restrict__ Ssum,
                                                 float* __restrict__ out) {
  const int b = blockIdx.x;                    // 0..2079
  const int nid = (b & 7) * 260 + (b >> 3);    // XCD-chunked, bijective
  int ti = (int)((129.0 - sqrt(129.0 * 129.0 - 8.0 * (double)nid)) * 0.5);
  while (64 * ti - ti * (ti - 1) / 2 > nid) --ti;
  while (64 * (ti + 1) - (ti + 1) * ti / 2 <= nid) ++ti;
  const int tj = ti + (nid - (64 * ti - ti * (ti - 1) / 2));

  __shared__ __bf16 As[128][64];
  __shared__ __bf16 Bs[128][64];
  __shared__ float sqi[128], sqj[128];
  __shared__ float wred[4];
  const int t = threadIdx.x;
  const int wid = t >> 6, lane = t & 63;
  const int wr = wid >> 1, wc = wid & 1;
  const int n16 = lane & 15, q = lane >> 4;
  const int sx = (n16 & 7) << 3;     // read-side swizzle (element units)
  const int lr = lane >> 3;          // 0..7: row within 8-row DMA chunk
  const int ls = lane & 7;           // 0..7: 16B slot within row

  const float g = scal[1];           // log2e / (bw*16)
  if (t < 128) sqi[t] = sq[ti * 128 + t] * g;          // pre-scaled by g
  else         sqj[t - 128] = sq[tj * 128 + (t - 128)] * g;

  f32x4 acc[4][4];
  f32x4 zero = {0.f, 0.f, 0.f, 0.f};
  for (int i = 0; i < 4; ++i)
    for (int j = 0; j < 4; ++j) acc[i][j] = zero;

  // pre-swizzled per-lane global source: LDS slot ls of row r holds global
  // slot ls^(r&7); r&7 == lr for every chunk (rows step by 8).
  const __bf16* gA = tot + (size_t)(ti * 128 + wid * 32 + lr) * 256 + ((ls ^ lr) << 3);
  const __bf16* gB = tot + (size_t)(tj * 128 + wid * 32 + lr) * 256 + ((ls ^ lr) << 3);

  for (int it = 0; it < 4; ++it) {
    const int kc = it * 64;
#pragma unroll
    for (int p = 0; p < 4; ++p) {
      gload_lds16(gA + p * 8 * 256 + kc, &As[wid * 32 + p * 8][0]);
      gload_lds16(gB + p * 8 * 256 + kc, &Bs[wid * 32 + p * 8][0]);
    }
    __syncthreads();   // implicit vmcnt(0): buffer ready (also publishes sqi/sqj)
    __builtin_amdgcn_s_setprio(1);
#pragma unroll
    for (int ks = 0; ks < 2; ++ks) {
      bf16x8 af[4], bfr[4];
#pragma unroll
      for (int f = 0; f < 4; ++f) {
        af[f]  = *(const bf16x8*)&As[wr * 64 + f * 16 + n16][(ks * 32 + q * 8) ^ sx];
        bfr[f] = *(const bf16x8*)&Bs[wc * 64 + f * 16 + n16][(ks * 32 + q * 8) ^ sx];
      }
      for (int fr = 0; fr < 4; ++fr)
        for (int fc = 0; fc < 4; ++fc)
          acc[fr][fc] = __builtin_amdgcn_mfma_f32_16x16x32_bf16(af[fr], bfr[fc], acc[fr][fc], 0, 0, 0);
    }
    __builtin_amdgcn_s_setprio(0);
    __syncthreads();   // all reads done before next stage overwrites
  }

  // epilogue: arg = 2g*acc - (g*si + g*sj); ksum = u+u2+u4+u8+u16, u=exp2(arg)
  const float twog = 2.f * g;
  float lsum = 0.f;
  for (int fr = 0; fr < 4; ++fr) {
    for (int r = 0; r < 4; ++r) {
      float gsi = sqi[wr * 64 + fr * 16 + q * 4 + r];
      for (int fc = 0; fc < 4; ++fc) {
        float gsj = sqj[wc * 64 + fc * 16 + n16];
        float u = exp2f(fmaf(twog, acc[fr][fc][r], -(gsi + gsj)));
        float u2 = u * u, u4 = u2 * u2, u8 = u4 * u4;
        float s1 = fmaf(u8, u8, u8);           // u16 + u8
        lsum += (u + u2) + (u4 + s1);
      }
    }
  }
  for (int off = 32; off; off >>= 1) lsum += __shfl_down(lsum, off, 64);
  if (lane == 0) wred[wid] = lsum;
  __syncthreads();
  if (t == 0) {
    float blocksum = wred[0] + wred[1] + wred[2] + wred[3];
    float sgn = ((ti < 32) == (tj < 32)) ? 1.f : -1.f;
    float wgt = (ti == tj) ? sgn : 2.f * sgn;
    atomicAdd(Ssum, wgt * blocksum);
    __threadfence();
    unsigned int* cnt = (unsigned int*)(Ssum + 3);   // scal[3], memset to 0
    unsigned int c = atomicAdd(cnt, 1u);
    if (c == 2079u) {
      float totS = atomicAdd(Ssum, 0.0f);            // coherent read of full sum
      out[1048576] = -(totS / 16777216.0f);
    }
  }
}

extern "C" void kernel_launch(void* const* d_in, const int* in_sizes, int n_in,
                              void* d_out, int out_size, void* d_ws, size_t ws_size,
                              hipStream_t stream) {
  const float* x    = (const float*)d_in[0];
  const float* Waux = (const float*)d_in[1];
  const float* baux = (const float*)d_in[2];
  const float* W    = (const float*)d_in[3];
  const float* bias = (const float*)d_in[4];
  float* out = (float*)d_out;

  char* ws = (char*)d_ws;
  __bf16* totalbf = (__bf16*)ws;                    // 8192*256*2 = 4,194,304 B
  float* sq      = (float*)(ws + 4194304);          // 8192 f32
  float* colsum  = (float*)(ws + 4227072);          // 256 f32
  float* scal    = (float*)(ws + 4228096);          // [0]=Ssum [1]=g4l2 [2]=bw [3]=cnt
  float* gates   = (float*)(ws + 4228160);          // 4096*2 f32

  // zero the atomic accumulators (colsum + scalars+counter)
  hipMemsetAsync(ws + 4227072, 0, 1024 + 64, stream);

  k_gates<<<1024, 256, 0, stream>>>(x, Waux, baux, gates);
  k_outs<<<dim3(8, 64), 256, 0, stream>>>(x, W, bias, totalbf);
  k_sqc<<<128, 256, 0, stream>>>(totalbf, gates, sq, colsum, out);
  k_bw<<<1, 256, 0, stream>>>(sq, colsum, scal);
  k_gram<<<2080, 256, 0, stream>>>(totalbf, sq, scal, scal, out);
}